// Round 1
// baseline (356.122 us; speedup 1.0000x reference)
//
#include <hip/hip_runtime.h>

// Problem constants
#define NB 16
#define CC 512
#define WW 4096
#define FD 512
#define NMASK 1024          // NUM_MASKS * MASK_WIDTH
#define T_COMB 11264        // 1024 masked + 10240 negative rows
#define OUT0_ELEMS (NB*CC*WW)   // 33554432 floats

// Workspace layout (bytes):
//   [0, 256KB)           : int32 lookup[N*W]  (flat pos -> combined row g, or -1)
//   [256KB, 768KB)       : bf16 Wq  [512][512]
//   [768KB, ~12.3MB)     : bf16 A   [11264][512]
#define WS_LOOKUP_OFF 0
#define WS_WQ_OFF     262144
#define WS_A_OFF      786432

typedef __attribute__((ext_vector_type(8))) short short8;
typedef __attribute__((ext_vector_type(4))) float f32x4;

__device__ __forceinline__ unsigned short f2bf(float x) {
  unsigned int u = __builtin_bit_cast(unsigned int, x);
  u += 0x7fffu + ((u >> 16) & 1u);   // round-to-nearest-even
  return (unsigned short)(u >> 16);
}

__device__ __forceinline__ void gload_lds16(const void* gp, void* lp) {
  __builtin_amdgcn_global_load_lds(
      (__attribute__((address_space(1))) void*)(gp),
      (__attribute__((address_space(3))) void*)(lp),
      16, 0, 0);
}

// K0: single block builds the flat-position -> combined-row lookup (no inter-block race).
__global__ __launch_bounds__(1024) void build_lookup_k(
    const int* __restrict__ pack_idx, const int* __restrict__ masked_idx,
    const int* __restrict__ neg_idx, int* __restrict__ lookup) {
  int tid = threadIdx.x;
  for (int i = tid; i < NB * WW; i += 1024) lookup[i] = -1;
  __syncthreads();
  for (int g = tid; g < T_COMB; g += 1024) {
    int pidx = (g < NMASK) ? masked_idx[g] : neg_idx[g - NMASK];
    lookup[pack_idx[pidx]] = g;
  }
}

// K1: streaming copy (valid->copy, invalid->0, masked->mask_emb) fused with
// bf16 A-row gather-scatter and Wq bf16 conversion (role-split blocks).
__global__ __launch_bounds__(256) void fused_copy_k(
    const float* __restrict__ in, const int* __restrict__ seq_len,
    const int* __restrict__ lookup, const float* __restrict__ mask_emb,
    const float* __restrict__ Wq, float* __restrict__ out0,
    unsigned short* __restrict__ A_ws, unsigned short* __restrict__ Wq_ws) {
  if (blockIdx.x >= 2048) {
    // Wq fp32 -> bf16: 262144 elems = 65536 float4 over 64 blocks
    int b2 = blockIdx.x - 2048;
    const float4* wq4 = (const float4*)Wq;
    for (int it = 0; it < 4; ++it) {
      int i4 = it * 16384 + b2 * 256 + (int)threadIdx.x;
      float4 v = wq4[i4];
      ushort4 o;
      o.x = f2bf(v.x); o.y = f2bf(v.y); o.z = f2bf(v.z); o.w = f2bf(v.w);
      ((ushort4*)Wq_ws)[i4] = o;
    }
    return;
  }
  const float4* in4 = (const float4*)in;
  const int4* lk4 = (const int4*)lookup;
  float4* out4 = (float4*)out0;
  for (int it = 0; it < 16; ++it) {
    int i4 = it * 524288 + (int)blockIdx.x * 256 + (int)threadIdx.x;
    int e = i4 << 2;               // flat element index into (N,C,1,W)
    int w = e & (WW - 1);
    int c = (e >> 12) & (CC - 1);
    int n = e >> 21;
    float4 v = in4[i4];
    int L = seq_len[n];
    int4 g4 = lk4[(n * WW + w) >> 2];
    float vv[4] = {v.x, v.y, v.z, v.w};
    int gg[4] = {g4.x, g4.y, g4.z, g4.w};
    float o[4];
#pragma unroll
    for (int k = 0; k < 4; ++k) {
      float val = (w + k < L) ? vv[k] : 0.0f;
      int g = gg[k];
      if (g >= 0) {
        A_ws[g * CC + c] = f2bf(vv[k]);              // pre-mask value for GEMM
        if (g < NMASK) val = mask_emb[(g & 3) * CC + c];
      }
      o[k] = val;
    }
    float4 ov = {o[0], o[1], o[2], o[3]};
    out4[i4] = ov;
  }
}

// K2: bf16 MFMA GEMM  out[m,f] = sum_c A[m,c]*Wq[f,c] + bq[f]
// M=11264, N=512, K=512.  128x128 block tile, 4 waves (2x2), 4x4 16x16 frags/wave.
__global__ __launch_bounds__(256) void gemm_k(
    const unsigned short* __restrict__ A, const unsigned short* __restrict__ B,
    const float* __restrict__ bq, float* __restrict__ out) {
  __shared__ unsigned short As[128 * 32];   // 8 KB
  __shared__ unsigned short Bs[128 * 32];   // 8 KB
  const int tid = threadIdx.x;
  const int lane = tid & 63;
  const int quad = lane >> 4;
  const int r16 = lane & 15;
  const int wv = tid >> 6;
  const int bm = blockIdx.x * 128;
  const int bf = blockIdx.y * 128;
  const int wm = (wv & 1) * 64;
  const int wf = (wv >> 1) * 64;
  const int wbase = tid & ~63;   // wave-uniform

  f32x4 acc[4][4];
#pragma unroll
  for (int mi = 0; mi < 4; ++mi)
#pragma unroll
    for (int fi = 0; fi < 4; ++fi)
      acc[mi][fi] = (f32x4){0.f, 0.f, 0.f, 0.f};

  for (int k0 = 0; k0 < 512; k0 += 32) {
    // Stage 128x32 bf16 tiles of A and B: 512 16B-chunks each, 256 thr x 2 iters.
    // LDS dest = wave-uniform base + lane*16 (global_load_lds constraint).
#pragma unroll
    for (int it = 0; it < 2; ++it) {
      int ch = it * 256 + tid;         // chunk in [0,512)
      int row = ch >> 2;               // [0,128)
      int cg = ch & 3;                 // 8-bf16 group in [0,4)
      int ubase = (it * 256 + wbase) * 8;   // ushort index of wave's chunk base
      gload_lds16(A + (size_t)(bm + row) * 512 + k0 + cg * 8, &As[ubase]);
      gload_lds16(B + (size_t)(bf + row) * 512 + k0 + cg * 8, &Bs[ubase]);
    }
    asm volatile("s_waitcnt vmcnt(0)" ::: "memory");
    __syncthreads();

    short8 a[4], b[4];
#pragma unroll
    for (int mi = 0; mi < 4; ++mi)
      a[mi] = *(const short8*)&As[(wm + mi * 16 + r16) * 32 + quad * 8];
#pragma unroll
    for (int fi = 0; fi < 4; ++fi)
      b[fi] = *(const short8*)&Bs[(wf + fi * 16 + r16) * 32 + quad * 8];
#pragma unroll
    for (int mi = 0; mi < 4; ++mi)
#pragma unroll
      for (int fi = 0; fi < 4; ++fi)
        acc[mi][fi] = __builtin_amdgcn_mfma_f32_16x16x32_bf16(
            a[mi], b[fi], acc[mi][fi], 0, 0, 0);
    __syncthreads();
  }

  // Epilogue: C/D layout col = lane&15 (f), row = quad*4 + reg (m).
#pragma unroll
  for (int fi = 0; fi < 4; ++fi) {
    int f = bf + wf + fi * 16 + r16;
    float bqv = bq[f];
#pragma unroll
    for (int mi = 0; mi < 4; ++mi) {
      int m0 = bm + wm + mi * 16 + quad * 4;
#pragma unroll
      for (int r = 0; r < 4; ++r)
        out[(size_t)(m0 + r) * 512 + f] = acc[mi][fi][r] + bqv;
    }
  }
}

extern "C" void kernel_launch(void* const* d_in, const int* in_sizes, int n_in,
                              void* d_out, int out_size, void* d_ws, size_t ws_size,
                              hipStream_t stream) {
  const float* inputs    = (const float*)d_in[0];
  const int*   seq_len   = (const int*)d_in[1];
  const int*   pack_idx  = (const int*)d_in[2];
  const int*   masked_idx= (const int*)d_in[3];
  const int*   neg_idx   = (const int*)d_in[4];
  const float* mask_emb  = (const float*)d_in[5];
  const float* Wq        = (const float*)d_in[6];
  const float* bq        = (const float*)d_in[7];
  float* out = (float*)d_out;
  char* ws = (char*)d_ws;
  int* lookup = (int*)(ws + WS_LOOKUP_OFF);
  unsigned short* wqb = (unsigned short*)(ws + WS_WQ_OFF);
  unsigned short* aws = (unsigned short*)(ws + WS_A_OFF);

  build_lookup_k<<<1, 1024, 0, stream>>>(pack_idx, masked_idx, neg_idx, lookup);
  fused_copy_k<<<2112, 256, 0, stream>>>(inputs, seq_len, lookup, mask_emb, Wq,
                                         out, aws, wqb);
  gemm_k<<<dim3(88, 4), 256, 0, stream>>>(aws, wqb, bq, out + OUT0_ELEMS);
}

// Round 2
// 300.699 us; speedup vs baseline: 1.1843x; 1.1843x over previous
//
#include <hip/hip_runtime.h>

// Problem constants
#define NB 16
#define CC 512
#define WW 4096
#define FD 512
#define NMASK 1024          // NUM_MASKS * MASK_WIDTH
#define T_COMB 11264        // 1024 masked + 10240 negative rows
#define OUT0_ELEMS (NB*CC*WW)   // 33554432 floats

// Workspace layout (bytes):
//   [0, 256KB)           : int32 lookup[N*W]  (flat pos -> combined row g, or -1)
//   [256KB, 768KB)       : bf16 Wq  [512][512]
//   [768KB, ~12.3MB)     : bf16 A   [11264][512]
#define WS_LOOKUP_OFF 0
#define WS_WQ_OFF     262144
#define WS_A_OFF      786432

#define S_LDS 36            // ushort stride per c-row in the transpose tile

typedef __attribute__((ext_vector_type(8))) short short8;
typedef __attribute__((ext_vector_type(4))) float f32x4;

__device__ __forceinline__ unsigned short f2bf(float x) {
  unsigned int u = __builtin_bit_cast(unsigned int, x);
  u += 0x7fffu + ((u >> 16) & 1u);   // round-to-nearest-even
  return (unsigned short)(u >> 16);
}

__device__ __forceinline__ void gload_lds16(const void* gp, void* lp) {
  __builtin_amdgcn_global_load_lds(
      (__attribute__((address_space(1))) void*)(gp),
      (__attribute__((address_space(3))) void*)(lp),
      16, 0, 0);
}

// K0b: scatter combined row ids into the (memset to -1) lookup table.
__global__ __launch_bounds__(256) void scatter_lookup_k(
    const int* __restrict__ pack_idx, const int* __restrict__ masked_idx,
    const int* __restrict__ neg_idx, int* __restrict__ lookup) {
  int g = blockIdx.x * 256 + threadIdx.x;          // [0, 11264)
  int pidx = (g < NMASK) ? masked_idx[g] : neg_idx[g - NMASK];
  lookup[pack_idx[pidx]] = g;
}

// K1: tile-transpose streaming copy. Block = (n, all c, 32 w).
// Phase 1: coalesced in-read + out0 write (+ mask overwrite), bf16 pre-mask
//          values into padded LDS tile [c][w].
// Phase 2: per selected w-slot, 256 threads write the A row coalesced.
__global__ __launch_bounds__(256) void fused_copy_k(
    const float* __restrict__ in, const int* __restrict__ seq_len,
    const int* __restrict__ lookup, const float* __restrict__ mask_emb,
    const float* __restrict__ Wq, float* __restrict__ out0,
    unsigned short* __restrict__ A_ws, unsigned short* __restrict__ Wq_ws) {
  if (blockIdx.x >= 2048) {
    // Wq fp32 -> bf16: 262144 elems = 65536 float4 over 64 blocks
    int b2 = blockIdx.x - 2048;
    const float4* wq4 = (const float4*)Wq;
    for (int it = 0; it < 4; ++it) {
      int i4 = it * 16384 + b2 * 256 + (int)threadIdx.x;
      float4 v = wq4[i4];
      ushort4 o;
      o.x = f2bf(v.x); o.y = f2bf(v.y); o.z = f2bf(v.z); o.w = f2bf(v.w);
      ((ushort4*)Wq_ws)[i4] = o;
    }
    return;
  }
  __shared__ unsigned short tile[CC * S_LDS];   // 36 KB
  __shared__ int g_s[32];
  const int tid = threadIdx.x;
  const int bx = blockIdx.x;
  const int n = bx >> 7;                 // 16 n-lines
  const int w0 = (bx & 127) * 32;        // 128 w-tiles per line
  if (tid < 32) g_s[tid] = lookup[n * WW + w0 + tid];

  const int wl4 = (tid & 7) * 4;         // this thread's 4-w slot
  const int w = w0 + wl4;
  const int4 g4 = *(const int4*)&lookup[n * WW + w];   // 16B aligned
  const int L = seq_len[n];
  const int gg[4] = {g4.x, g4.y, g4.z, g4.w};

  const float4* in4 = (const float4*)in;
  float4* out4 = (float4*)out0;
  const size_t rowbase = ((size_t)n << 21) + (size_t)w;   // element index

#pragma unroll 4
  for (int it = 0; it < 16; ++it) {
    int c = it * 32 + (tid >> 3);
    size_t e = rowbase + ((size_t)c << 12);
    float4 v = in4[e >> 2];
    float vv[4] = {v.x, v.y, v.z, v.w};
    // pre-mask bf16 into the transpose tile (8B-aligned ushort4)
    ushort4 bf;
    bf.x = f2bf(vv[0]); bf.y = f2bf(vv[1]); bf.z = f2bf(vv[2]); bf.w = f2bf(vv[3]);
    *(ushort4*)&tile[c * S_LDS + wl4] = bf;
    float o[4];
#pragma unroll
    for (int k = 0; k < 4; ++k) {
      float val = (w + k < L) ? vv[k] : 0.0f;
      int g = gg[k];
      if ((unsigned)g < (unsigned)NMASK) val = mask_emb[(g & 3) * CC + c];
      o[k] = val;
    }
    float4 ov = {o[0], o[1], o[2], o[3]};
    out4[e >> 2] = ov;
  }
  __syncthreads();

  // Phase 2: coalesced A-row emission (uniform branch per slot).
  const int c2 = tid * 2;
  for (int wl = 0; wl < 32; ++wl) {
    int g = g_s[wl];
    if (g < 0) continue;
    ushort2 val;
    val.x = tile[c2 * S_LDS + wl];
    val.y = tile[(c2 + 1) * S_LDS + wl];
    *(ushort2*)&A_ws[(size_t)g * CC + c2] = val;
  }
}

// K2: bf16 MFMA GEMM  out[m,f] = sum_c A[m,c]*Wq[f,c] + bq[f]
// M=11264, N=512, K=512.  128x128 block tile, 4 waves (2x2), 4x4 16x16 frags/wave.
__global__ __launch_bounds__(256) void gemm_k(
    const unsigned short* __restrict__ A, const unsigned short* __restrict__ B,
    const float* __restrict__ bq, float* __restrict__ out) {
  __shared__ unsigned short As[128 * 32];   // 8 KB
  __shared__ unsigned short Bs[128 * 32];   // 8 KB
  const int tid = threadIdx.x;
  const int lane = tid & 63;
  const int quad = lane >> 4;
  const int r16 = lane & 15;
  const int wv = tid >> 6;
  const int bm = blockIdx.x * 128;
  const int bf = blockIdx.y * 128;
  const int wm = (wv & 1) * 64;
  const int wf = (wv >> 1) * 64;
  const int wbase = tid & ~63;   // wave-uniform

  f32x4 acc[4][4];
#pragma unroll
  for (int mi = 0; mi < 4; ++mi)
#pragma unroll
    for (int fi = 0; fi < 4; ++fi)
      acc[mi][fi] = (f32x4){0.f, 0.f, 0.f, 0.f};

  for (int k0 = 0; k0 < 512; k0 += 32) {
#pragma unroll
    for (int it = 0; it < 2; ++it) {
      int ch = it * 256 + tid;         // chunk in [0,512)
      int row = ch >> 2;               // [0,128)
      int cg = ch & 3;                 // 8-bf16 group in [0,4)
      int ubase = (it * 256 + wbase) * 8;   // ushort index of wave's chunk base
      gload_lds16(A + (size_t)(bm + row) * 512 + k0 + cg * 8, &As[ubase]);
      gload_lds16(B + (size_t)(bf + row) * 512 + k0 + cg * 8, &Bs[ubase]);
    }
    asm volatile("s_waitcnt vmcnt(0)" ::: "memory");
    __syncthreads();

    short8 a[4], b[4];
#pragma unroll
    for (int mi = 0; mi < 4; ++mi)
      a[mi] = *(const short8*)&As[(wm + mi * 16 + r16) * 32 + quad * 8];
#pragma unroll
    for (int fi = 0; fi < 4; ++fi)
      b[fi] = *(const short8*)&Bs[(wf + fi * 16 + r16) * 32 + quad * 8];
#pragma unroll
    for (int mi = 0; mi < 4; ++mi)
#pragma unroll
      for (int fi = 0; fi < 4; ++fi)
        acc[mi][fi] = __builtin_amdgcn_mfma_f32_16x16x32_bf16(
            a[mi], b[fi], acc[mi][fi], 0, 0, 0);
    __syncthreads();
  }

  // Epilogue: C/D layout col = lane&15 (f), row = quad*4 + reg (m).
#pragma unroll
  for (int fi = 0; fi < 4; ++fi) {
    int f = bf + wf + fi * 16 + r16;
    float bqv = bq[f];
#pragma unroll
    for (int mi = 0; mi < 4; ++mi) {
      int m0 = bm + wm + mi * 16 + quad * 4;
#pragma unroll
      for (int r = 0; r < 4; ++r)
        out[(size_t)(m0 + r) * 512 + f] = acc[mi][fi][r] + bqv;
    }
  }
}

extern "C" void kernel_launch(void* const* d_in, const int* in_sizes, int n_in,
                              void* d_out, int out_size, void* d_ws, size_t ws_size,
                              hipStream_t stream) {
  const float* inputs    = (const float*)d_in[0];
  const int*   seq_len   = (const int*)d_in[1];
  const int*   pack_idx  = (const int*)d_in[2];
  const int*   masked_idx= (const int*)d_in[3];
  const int*   neg_idx   = (const int*)d_in[4];
  const float* mask_emb  = (const float*)d_in[5];
  const float* Wq        = (const float*)d_in[6];
  const float* bq        = (const float*)d_in[7];
  float* out = (float*)d_out;
  char* ws = (char*)d_ws;
  int* lookup = (int*)(ws + WS_LOOKUP_OFF);
  unsigned short* wqb = (unsigned short*)(ws + WS_WQ_OFF);
  unsigned short* aws = (unsigned short*)(ws + WS_A_OFF);

  hipMemsetAsync(lookup, 0xFF, NB * WW * sizeof(int), stream);  // all -1
  scatter_lookup_k<<<44, 256, 0, stream>>>(pack_idx, masked_idx, neg_idx, lookup);
  fused_copy_k<<<2112, 256, 0, stream>>>(inputs, seq_len, lookup, mask_emb, Wq,
                                         out, aws, wqb);
  gemm_k<<<dim3(88, 4), 256, 0, stream>>>(aws, wqb, bq, out + OUT0_ELEMS);
}

// Round 3
// 296.117 us; speedup vs baseline: 1.2026x; 1.0155x over previous
//
#include <hip/hip_runtime.h>

// Problem constants
#define NB 16
#define CC 512
#define WW 4096
#define FD 512
#define NMASK 1024          // NUM_MASKS * MASK_WIDTH
#define T_COMB 11264        // 1024 masked + 10240 negative rows
#define OUT0_ELEMS (NB*CC*WW)   // 33554432 floats

// Workspace layout (bytes):
//   [0, 256KB)           : int32 lookup[N*W]  (flat pos -> combined row g, or -1)
//   [256KB, 768KB)       : bf16 Wq  [512][512]
//   [768KB, ~12.3MB)     : bf16 A   [11264][512]
#define WS_LOOKUP_OFF 0
#define WS_WQ_OFF     262144
#define WS_A_OFF      786432

#define S_LDS 36            // ushort stride per c-row in the transpose tile

typedef __attribute__((ext_vector_type(8))) short short8;
typedef __attribute__((ext_vector_type(4))) float f32x4;

__device__ __forceinline__ unsigned short f2bf(float x) {
  unsigned int u = __builtin_bit_cast(unsigned int, x);
  u += 0x7fffu + ((u >> 16) & 1u);   // round-to-nearest-even
  return (unsigned short)(u >> 16);
}

__device__ __forceinline__ void gload_lds16(const void* gp, void* lp) {
  __builtin_amdgcn_global_load_lds(
      (__attribute__((address_space(1))) void*)(gp),
      (__attribute__((address_space(3))) void*)(lp),
      16, 0, 0);
}

// K0b: scatter combined row ids into the (memset to -1) lookup table.
__global__ __launch_bounds__(256) void scatter_lookup_k(
    const int* __restrict__ pack_idx, const int* __restrict__ masked_idx,
    const int* __restrict__ neg_idx, int* __restrict__ lookup) {
  int g = blockIdx.x * 256 + threadIdx.x;          // [0, 11264)
  int pidx = (g < NMASK) ? masked_idx[g] : neg_idx[g - NMASK];
  lookup[pack_idx[pidx]] = g;
}

// K1: tile-transpose streaming copy. Block = (n, all c, 32 w).
// seq_len is a multiple of 128, tiles are 32-wide -> each tile is all-valid
// or all-invalid. Invalid: pure zero-fill (no reads). Valid: coalesced
// in-read + out0 write (mask path gated by wave-uniform ballot), bf16
// pre-mask values into padded LDS tile [c][w]; phase 2 emits A rows
// coalesced, iterating a ballot-derived slot bitmask.
__global__ __launch_bounds__(256) void fused_copy_k(
    const float* __restrict__ in, const int* __restrict__ seq_len,
    const int* __restrict__ lookup, const float* __restrict__ mask_emb,
    const float* __restrict__ Wq, float* __restrict__ out0,
    unsigned short* __restrict__ A_ws, unsigned short* __restrict__ Wq_ws) {
  if (blockIdx.x >= 2048) {
    // Wq fp32 -> bf16: 262144 elems = 65536 float4 over 64 blocks
    int b2 = blockIdx.x - 2048;
    const float4* wq4 = (const float4*)Wq;
#pragma unroll
    for (int it = 0; it < 4; ++it) {
      int i4 = it * 16384 + b2 * 256 + (int)threadIdx.x;
      float4 v = wq4[i4];
      ushort4 o;
      o.x = f2bf(v.x); o.y = f2bf(v.y); o.z = f2bf(v.z); o.w = f2bf(v.w);
      ((ushort4*)Wq_ws)[i4] = o;
    }
    return;
  }
  const int tid = threadIdx.x;
  const int bx = blockIdx.x;
  const int n = bx >> 7;                 // 16 n-lines
  const int w0 = (bx & 127) * 32;        // 128 w-tiles per line
  const int wl4 = (tid & 7) * 4;         // this thread's 4-w slot
  const int w = w0 + wl4;
  const int c0 = tid >> 3;               // 0..31
  const size_t rowbase = ((size_t)n << 21) + (size_t)w;   // element index
  float4* out4 = (float4*)out0;
  const int L = seq_len[n];

  if (w0 + 32 > L) {
    // fully-invalid tile: zero-fill out0, nothing else to do
    float4 z = {0.f, 0.f, 0.f, 0.f};
#pragma unroll
    for (int it = 0; it < 16; ++it) {
      int c = it * 32 + c0;
      out4[(rowbase + ((size_t)c << 12)) >> 2] = z;
    }
    return;
  }

  __shared__ unsigned short tile[CC * S_LDS];   // 36 KB
  __shared__ int g_s[32];
  if (tid < 32) g_s[tid] = lookup[n * WW + w0 + tid];

  const int4 g4 = *(const int4*)&lookup[n * WW + w];   // 16B aligned
  const int gg[4] = {g4.x, g4.y, g4.z, g4.w};
  bool lane_has_mask = ((unsigned)gg[0] < (unsigned)NMASK) |
                       ((unsigned)gg[1] < (unsigned)NMASK) |
                       ((unsigned)gg[2] < (unsigned)NMASK) |
                       ((unsigned)gg[3] < (unsigned)NMASK);
  // every wave contains all 8 w4-groups -> ballot is block-wide truth
  bool has_mask = __ballot(lane_has_mask) != 0ull;

  const float4* in4 = (const float4*)in;
#pragma unroll
  for (int it = 0; it < 16; ++it) {
    int c = it * 32 + c0;
    size_t i4 = (rowbase + ((size_t)c << 12)) >> 2;
    float4 v = in4[i4];
    ushort4 bf;
    bf.x = f2bf(v.x); bf.y = f2bf(v.y); bf.z = f2bf(v.z); bf.w = f2bf(v.w);
    *(ushort4*)&tile[c * S_LDS + wl4] = bf;
    if (has_mask) {   // wave-uniform branch
      float o[4] = {v.x, v.y, v.z, v.w};
#pragma unroll
      for (int k = 0; k < 4; ++k)
        if ((unsigned)gg[k] < (unsigned)NMASK)
          o[k] = mask_emb[(gg[k] & 3) * CC + c];
      v.x = o[0]; v.y = o[1]; v.z = o[2]; v.w = o[3];
    }
    out4[i4] = v;
  }
  __syncthreads();

  // Phase 2: coalesced A-row emission over selected slots only.
  const int lane = tid & 63;
  bool sel = (lane < 32) && (g_s[lane & 31] >= 0);
  unsigned smask = (unsigned)__ballot(sel);
  const int c2 = tid * 2;
  while (smask) {
    int wl = __builtin_ctz(smask);
    smask &= smask - 1;
    int g = g_s[wl];
    ushort2 val;
    val.x = tile[c2 * S_LDS + wl];
    val.y = tile[(c2 + 1) * S_LDS + wl];
    *(ushort2*)&A_ws[(size_t)g * CC + c2] = val;
  }
}

// K2: bf16 MFMA GEMM  out[m,f] = sum_c A[m,c]*Wq[f,c] + bq[f]
// M=11264, N=512, K=512.  64x128 block tile (704 blocks -> better CU
// balance than 128x128's 352), 4 waves (2x2), 2x4 16x16 frags/wave.
__global__ __launch_bounds__(256) void gemm_k(
    const unsigned short* __restrict__ A, const unsigned short* __restrict__ B,
    const float* __restrict__ bq, float* __restrict__ out) {
  __shared__ unsigned short As[64 * 32];    // 4 KB
  __shared__ unsigned short Bs[128 * 32];   // 8 KB
  const int tid = threadIdx.x;
  const int lane = tid & 63;
  const int quad = lane >> 4;
  const int r16 = lane & 15;
  const int wv = tid >> 6;
  const int bm = blockIdx.x * 64;
  const int bf = blockIdx.y * 128;
  const int wm = (wv & 1) * 32;
  const int wf = (wv >> 1) * 64;
  const int wbase = tid & ~63;   // wave-uniform

  f32x4 acc[2][4];
#pragma unroll
  for (int mi = 0; mi < 2; ++mi)
#pragma unroll
    for (int fi = 0; fi < 4; ++fi)
      acc[mi][fi] = (f32x4){0.f, 0.f, 0.f, 0.f};

  for (int k0 = 0; k0 < 512; k0 += 32) {
    {
      // A tile: 64 rows x 32 k = 256 16B-chunks, one pass
      int row = tid >> 2, cg = tid & 3;
      gload_lds16(A + (size_t)(bm + row) * 512 + k0 + cg * 8, &As[wbase * 8]);
    }
#pragma unroll
    for (int it = 0; it < 2; ++it) {
      // B tile: 128 rows x 32 k = 512 chunks, two passes
      int ch = it * 256 + tid;
      int row = ch >> 2, cg = ch & 3;
      gload_lds16(B + (size_t)(bf + row) * 512 + k0 + cg * 8,
                  &Bs[(it * 256 + wbase) * 8]);
    }
    asm volatile("s_waitcnt vmcnt(0)" ::: "memory");
    __syncthreads();

    short8 a[2], b[4];
#pragma unroll
    for (int mi = 0; mi < 2; ++mi)
      a[mi] = *(const short8*)&As[(wm + mi * 16 + r16) * 32 + quad * 8];
#pragma unroll
    for (int fi = 0; fi < 4; ++fi)
      b[fi] = *(const short8*)&Bs[(wf + fi * 16 + r16) * 32 + quad * 8];
#pragma unroll
    for (int mi = 0; mi < 2; ++mi)
#pragma unroll
      for (int fi = 0; fi < 4; ++fi)
        acc[mi][fi] = __builtin_amdgcn_mfma_f32_16x16x32_bf16(
            a[mi], b[fi], acc[mi][fi], 0, 0, 0);
    __syncthreads();
  }

  // Epilogue: C/D layout col = lane&15 (f), row = quad*4 + reg (m).
#pragma unroll
  for (int fi = 0; fi < 4; ++fi) {
    int f = bf + wf + fi * 16 + r16;
    float bqv = bq[f];
#pragma unroll
    for (int mi = 0; mi < 2; ++mi) {
      int m0 = bm + wm + mi * 16 + quad * 4;
#pragma unroll
      for (int r = 0; r < 4; ++r)
        out[(size_t)(m0 + r) * 512 + f] = acc[mi][fi][r] + bqv;
    }
  }
}

extern "C" void kernel_launch(void* const* d_in, const int* in_sizes, int n_in,
                              void* d_out, int out_size, void* d_ws, size_t ws_size,
                              hipStream_t stream) {
  const float* inputs    = (const float*)d_in[0];
  const int*   seq_len   = (const int*)d_in[1];
  const int*   pack_idx  = (const int*)d_in[2];
  const int*   masked_idx= (const int*)d_in[3];
  const int*   neg_idx   = (const int*)d_in[4];
  const float* mask_emb  = (const float*)d_in[5];
  const float* Wq        = (const float*)d_in[6];
  const float* bq        = (const float*)d_in[7];
  float* out = (float*)d_out;
  char* ws = (char*)d_ws;
  int* lookup = (int*)(ws + WS_LOOKUP_OFF);
  unsigned short* wqb = (unsigned short*)(ws + WS_WQ_OFF);
  unsigned short* aws = (unsigned short*)(ws + WS_A_OFF);

  hipMemsetAsync(lookup, 0xFF, NB * WW * sizeof(int), stream);  // all -1
  scatter_lookup_k<<<44, 256, 0, stream>>>(pack_idx, masked_idx, neg_idx, lookup);
  fused_copy_k<<<2112, 256, 0, stream>>>(inputs, seq_len, lookup, mask_emb, Wq,
                                         out, aws, wqb);
  gemm_k<<<dim3(176, 4), 256, 0, stream>>>(aws, wqb, bq, out + OUT0_ELEMS);
}